// Round 1
// baseline (851.390 us; speedup 1.0000x reference)
//
#include <hip/hip_runtime.h>
#include <hip/hip_bf16.h>
#include <limits.h>

#define N 50000
#define E_ 800000
#define ETOT 850000          // E + N self loops
#define HH 128               // HEADS*HID
#define HEADS 8
#define HID 16
#define CLS 16
#define NEG 0.2f

__device__ __forceinline__ int f2ord(float f){ int i=__float_as_int(f); return i>=0? i : (i^0x7fffffff); }
__device__ __forceinline__ float ord2f(int i){ return __int_as_float(i>=0? i : (i^0x7fffffff)); }

__device__ __forceinline__ void edge_sd(const int* __restrict__ ei, int e, int& s, int& d){
  if(e < E_){ s = ei[e]; d = ei[E_ + e]; } else { s = d = e - E_; }
}

// ---------------- init ----------------
__global__ __launch_bounds__(256) void k_init(int* m1, float* den1, float* out1,
                                              int* m2, float* den2, float* outf){
  int i = blockIdx.x*256 + threadIdx.x;
  if(i < N*HEADS){ m1[i] = INT_MIN; den1[i] = 0.f; }
  if(i < N){ m2[i] = INT_MIN; den2[i] = 0.f; }
  if(i < N*HH) out1[i] = 0.f;
  if(i < N*CLS) outf[i] = 0.f;
}

// ---------------- GEMM1: h1[N,128] = x[N,128] @ W1[128,128] ----------------
__global__ __launch_bounds__(256) void k_gemm1(const float* __restrict__ x,
                                               const float* __restrict__ W,
                                               float* __restrict__ h1){
  __shared__ float Wl[128*128];               // 64 KiB
  int tid = threadIdx.x;
  const float4* W4 = (const float4*)W;
  float4* Wl4 = (float4*)Wl;
  #pragma unroll
  for(int i=0;i<16;i++) Wl4[tid + i*256] = W4[tid + i*256];
  __syncthreads();
  int col = tid & 127;
  int rg  = tid >> 7;
  int row0 = blockIdx.x*32 + rg*16;
  if(row0 >= N) return;
  int rmax = N - row0; if(rmax > 16) rmax = 16;
  float acc[16];
  #pragma unroll
  for(int r=0;r<16;r++) acc[r]=0.f;
  const float4* x4 = (const float4*)x;        // [N][32] float4
  for(int k4=0;k4<32;k4++){
    float w0 = Wl[(4*k4+0)*128+col];
    float w1 = Wl[(4*k4+1)*128+col];
    float w2 = Wl[(4*k4+2)*128+col];
    float w3 = Wl[(4*k4+3)*128+col];
    #pragma unroll
    for(int r=0;r<16;r++){
      if(r < rmax){
        float4 xv = x4[(size_t)(row0+r)*32 + k4];   // wave-uniform -> s_load
        acc[r] = fmaf(xv.x,w0, fmaf(xv.y,w1, fmaf(xv.z,w2, fmaf(xv.w,w3, acc[r]))));
      }
    }
  }
  for(int r=0;r<rmax;r++) h1[(size_t)(row0+r)*HH + col] = acc[r];
}

// ---------------- per-node attention logits, layer 1 ----------------
__global__ __launch_bounds__(256) void k_alpha1(const float* __restrict__ h1,
                                                const float* __restrict__ av_s,
                                                const float* __restrict__ av_d,
                                                float* __restrict__ as1, float* __restrict__ ad1){
  int id = blockIdx.x*256 + threadIdx.x;
  if(id >= N*HEADS) return;
  int i = id >> 3, h = id & 7;
  const float4* hv = (const float4*)(h1 + (size_t)i*HH + h*HID);
  const float4* a1 = (const float4*)(av_s + h*HID);
  const float4* a2 = (const float4*)(av_d + h*HID);
  float s=0.f, d=0.f;
  #pragma unroll
  for(int j=0;j<4;j++){
    float4 v=hv[j], p=a1[j], q=a2[j];
    s += v.x*p.x + v.y*p.y + v.z*p.z + v.w*p.w;
    d += v.x*q.x + v.y*q.y + v.z*q.z + v.w*q.w;
  }
  as1[id]=s; ad1[id]=d;
}

// ---------------- edge passes, layer 1 ----------------
__global__ __launch_bounds__(256) void k_edge_max1(const int* __restrict__ ei,
                                                   const float* __restrict__ as1,
                                                   const float* __restrict__ ad1,
                                                   int* __restrict__ m1){
  int id = blockIdx.x*256 + threadIdx.x;
  if(id >= ETOT*HEADS) return;
  int e = id >> 3, h = id & 7;
  int s,d; edge_sd(ei, e, s, d);
  float v = as1[s*HEADS+h] + ad1[d*HEADS+h];
  v = v >= 0.f ? v : NEG*v;
  atomicMax(&m1[d*HEADS+h], f2ord(v));
}

__global__ __launch_bounds__(256) void k_edge_sum1(const int* __restrict__ ei,
                                                   const float* __restrict__ as1,
                                                   const float* __restrict__ ad1,
                                                   const int* __restrict__ m1,
                                                   float* __restrict__ den1){
  int id = blockIdx.x*256 + threadIdx.x;
  if(id >= ETOT*HEADS) return;
  int e = id >> 3, h = id & 7;
  int s,d; edge_sd(ei, e, s, d);
  float v = as1[s*HEADS+h] + ad1[d*HEADS+h];
  v = v >= 0.f ? v : NEG*v;
  float w = expf(v - ord2f(m1[d*HEADS+h]));
  unsafeAtomicAdd(&den1[d*HEADS+h], w);
}

__global__ __launch_bounds__(256) void k_scatter1(const int* __restrict__ ei,
                                                  const float* __restrict__ as1,
                                                  const float* __restrict__ ad1,
                                                  const int* __restrict__ m1,
                                                  const float* __restrict__ den1,
                                                  const float* __restrict__ h1,
                                                  float* __restrict__ out1){
  int id = blockIdx.x*256 + threadIdx.x;     // ETOT*128 = 108.8M, fits int
  int e = id >> 7, c = id & 127;
  if(e >= ETOT) return;
  int h = c >> 4;
  int s,d; edge_sd(ei, e, s, d);
  float v = as1[s*HEADS+h] + ad1[d*HEADS+h];
  v = v >= 0.f ? v : NEG*v;
  float alpha = expf(v - ord2f(m1[d*HEADS+h])) / (den1[d*HEADS+h] + 1e-16f);
  unsafeAtomicAdd(&out1[(size_t)d*HH + c], alpha * h1[(size_t)s*HH + c]);
}

// ---------------- bias + ELU (in place on out1) ----------------
__global__ __launch_bounds__(256) void k_post1(float* __restrict__ out1, const float* __restrict__ b1){
  int i = blockIdx.x*256 + threadIdx.x;
  if(i >= N*HH) return;
  float v = out1[i] + b1[i & 127];
  out1[i] = v > 0.f ? v : expm1f(v);
}

// ---------------- GEMM2: h2[N,16] = h[N,128] @ W2[128,16] ----------------
__global__ __launch_bounds__(256) void k_gemm2(const float* __restrict__ h,
                                               const float* __restrict__ W2,
                                               float* __restrict__ h2){
  __shared__ float Wl[128*16];                // 8 KiB
  int tid = threadIdx.x;
  const float4* W4 = (const float4*)W2;
  float4* Wl4 = (float4*)Wl;
  Wl4[tid]       = W4[tid];
  Wl4[tid + 256] = W4[tid + 256];
  __syncthreads();
  int i = blockIdx.x*16 + (tid >> 4);
  int c = tid & 15;
  if(i >= N) return;
  const float4* h4 = (const float4*)(h + (size_t)i*HH);
  float acc = 0.f;
  #pragma unroll
  for(int k4=0;k4<32;k4++){
    float4 v = h4[k4];
    acc = fmaf(v.x, Wl[(4*k4+0)*16+c], acc);
    acc = fmaf(v.y, Wl[(4*k4+1)*16+c], acc);
    acc = fmaf(v.z, Wl[(4*k4+2)*16+c], acc);
    acc = fmaf(v.w, Wl[(4*k4+3)*16+c], acc);
  }
  h2[(size_t)i*CLS + c] = acc;
}

// ---------------- per-node attention logits, layer 2 ----------------
__global__ __launch_bounds__(256) void k_alpha2(const float* __restrict__ h2,
                                                const float* __restrict__ av_s,
                                                const float* __restrict__ av_d,
                                                float* __restrict__ as2, float* __restrict__ ad2){
  int i = blockIdx.x*256 + threadIdx.x;
  if(i >= N) return;
  const float4* h4 = (const float4*)(h2 + (size_t)i*CLS);
  const float4* s4 = (const float4*)av_s;
  const float4* d4 = (const float4*)av_d;
  float s=0.f, d=0.f;
  #pragma unroll
  for(int j=0;j<4;j++){
    float4 v=h4[j], a=s4[j], b=d4[j];
    s += v.x*a.x + v.y*a.y + v.z*a.z + v.w*a.w;
    d += v.x*b.x + v.y*b.y + v.z*b.z + v.w*b.w;
  }
  as2[i]=s; ad2[i]=d;
}

// ---------------- edge passes, layer 2 (heads=1) ----------------
__global__ __launch_bounds__(256) void k_edge_max2(const int* __restrict__ ei,
                                                   const float* __restrict__ as2,
                                                   const float* __restrict__ ad2,
                                                   int* __restrict__ m2){
  int e = blockIdx.x*256 + threadIdx.x;
  if(e >= ETOT) return;
  int s,d; edge_sd(ei, e, s, d);
  float v = as2[s] + ad2[d];
  v = v >= 0.f ? v : NEG*v;
  atomicMax(&m2[d], f2ord(v));
}

__global__ __launch_bounds__(256) void k_edge_sum2(const int* __restrict__ ei,
                                                   const float* __restrict__ as2,
                                                   const float* __restrict__ ad2,
                                                   const int* __restrict__ m2,
                                                   float* __restrict__ den2){
  int e = blockIdx.x*256 + threadIdx.x;
  if(e >= ETOT) return;
  int s,d; edge_sd(ei, e, s, d);
  float v = as2[s] + ad2[d];
  v = v >= 0.f ? v : NEG*v;
  float w = expf(v - ord2f(m2[d]));
  unsafeAtomicAdd(&den2[d], w);
}

__global__ __launch_bounds__(256) void k_scatter2(const int* __restrict__ ei,
                                                  const float* __restrict__ as2,
                                                  const float* __restrict__ ad2,
                                                  const int* __restrict__ m2,
                                                  const float* __restrict__ den2,
                                                  const float* __restrict__ h2,
                                                  float* __restrict__ outp){
  int id = blockIdx.x*256 + threadIdx.x;     // ETOT*16 = 13.6M
  int e = id >> 4, c = id & 15;
  if(e >= ETOT) return;
  int s,d; edge_sd(ei, e, s, d);
  float v = as2[s] + ad2[d];
  v = v >= 0.f ? v : NEG*v;
  float alpha = expf(v - ord2f(m2[d])) / (den2[d] + 1e-16f);
  unsafeAtomicAdd(&outp[(size_t)d*CLS + c], alpha * h2[(size_t)s*CLS + c]);
}

// ---------------- final bias ----------------
__global__ __launch_bounds__(256) void k_final(float* __restrict__ outp, const float* __restrict__ b2){
  int i = blockIdx.x*256 + threadIdx.x;
  if(i >= N*CLS) return;
  outp[i] += b2[i & 15];
}

extern "C" void kernel_launch(void* const* d_in, const int* in_sizes, int n_in,
                              void* d_out, int out_size, void* d_ws, size_t ws_size,
                              hipStream_t stream){
  const float* x     = (const float*)d_in[0];
  const int*   ei    = (const int*)  d_in[1];
  const float* W1    = (const float*)d_in[2];
  const float* av_s1 = (const float*)d_in[3];
  const float* av_d1 = (const float*)d_in[4];
  const float* b1    = (const float*)d_in[5];
  const float* W2    = (const float*)d_in[6];
  const float* av_s2 = (const float*)d_in[7];
  const float* av_d2 = (const float*)d_in[8];
  const float* b2    = (const float*)d_in[9];
  float* outp = (float*)d_out;

  char* p = (char*)d_ws;
  auto alloc = [&](size_t bytes){ char* q = p; p += (bytes + 255) & ~(size_t)255; return q; };
  float* h1   = (float*)alloc((size_t)N*HH*4);
  float* out1 = (float*)alloc((size_t)N*HH*4);
  float* as1  = (float*)alloc((size_t)N*HEADS*4);
  float* ad1  = (float*)alloc((size_t)N*HEADS*4);
  int*   m1   = (int*)  alloc((size_t)N*HEADS*4);
  float* den1 = (float*)alloc((size_t)N*HEADS*4);
  float* h2   = (float*)alloc((size_t)N*CLS*4);
  float* as2  = (float*)alloc((size_t)N*4);
  float* ad2  = (float*)alloc((size_t)N*4);
  int*   m2   = (int*)  alloc((size_t)N*4);
  float* den2 = (float*)alloc((size_t)N*4);

  k_init<<<(N*HH+255)/256, 256, 0, stream>>>(m1, den1, out1, m2, den2, outp);
  k_gemm1<<<(N+31)/32, 256, 0, stream>>>(x, W1, h1);
  k_alpha1<<<(N*HEADS+255)/256, 256, 0, stream>>>(h1, av_s1, av_d1, as1, ad1);
  k_edge_max1<<<(ETOT*HEADS+255)/256, 256, 0, stream>>>(ei, as1, ad1, m1);
  k_edge_sum1<<<(ETOT*HEADS+255)/256, 256, 0, stream>>>(ei, as1, ad1, m1, den1);
  k_scatter1<<<(int)(((long long)ETOT*HH+255)/256), 256, 0, stream>>>(ei, as1, ad1, m1, den1, h1, out1);
  k_post1<<<(N*HH+255)/256, 256, 0, stream>>>(out1, b1);
  k_gemm2<<<(N+15)/16, 256, 0, stream>>>(out1, W2, h2);
  k_alpha2<<<(N+255)/256, 256, 0, stream>>>(h2, av_s2, av_d2, as2, ad2);
  k_edge_max2<<<(ETOT+255)/256, 256, 0, stream>>>(ei, as2, ad2, m2);
  k_edge_sum2<<<(ETOT+255)/256, 256, 0, stream>>>(ei, as2, ad2, m2, den2);
  k_scatter2<<<(ETOT*CLS+255)/256, 256, 0, stream>>>(ei, as2, ad2, m2, den2, h2, outp);
  k_final<<<(N*CLS+255)/256, 256, 0, stream>>>(outp, b2);
}

// Round 2
// 544.656 us; speedup vs baseline: 1.5632x; 1.5632x over previous
//
#include <hip/hip_runtime.h>
#include <hip/hip_bf16.h>
#include <limits.h>
#include <math.h>

#define N 50000
#define E_ 800000
#define ETOT 850000          // E + N self loops
#define HH 128               // HEADS*HID
#define HEADS 8
#define HID 16
#define CLS 16
#define NEG 0.2f

// ---------------- CSR build ----------------
__global__ __launch_bounds__(256) void k_zero(int* __restrict__ deg){
  int i = blockIdx.x*256 + threadIdx.x;
  if(i < N) deg[i] = 0;
}

__global__ __launch_bounds__(256) void k_hist(const int* __restrict__ ei, int* __restrict__ deg){
  int e = blockIdx.x*256 + threadIdx.x;
  if(e >= ETOT) return;
  int d = (e < E_) ? ei[E_ + e] : e - E_;
  atomicAdd(&deg[d], 1);
}

// single-block exclusive scan over deg[N] -> off[N+1]; also seeds cursor[]
__global__ __launch_bounds__(1024) void k_scan(const int* __restrict__ deg,
                                               int* __restrict__ off,
                                               int* __restrict__ cursor){
  __shared__ int part[1024];
  const int ITEMS = (N + 1023) / 1024;   // 49
  int t = threadIdx.x;
  int base = t * ITEMS;
  int s = 0;
  for(int i=0;i<ITEMS;i++){ int idx=base+i; if(idx<N) s += deg[idx]; }
  part[t] = s;
  __syncthreads();
  for(int ofs=1; ofs<1024; ofs<<=1){
    int v = part[t];
    int add = (t >= ofs) ? part[t-ofs] : 0;
    __syncthreads();
    part[t] = v + add;
    __syncthreads();
  }
  int run = (t == 0) ? 0 : part[t-1];
  for(int i=0;i<ITEMS;i++){
    int idx = base+i;
    if(idx < N){ off[idx] = run; cursor[idx] = run; run += deg[idx]; }
  }
  if(t == 1023) off[N] = part[1023];
}

__global__ __launch_bounds__(256) void k_fill(const int* __restrict__ ei,
                                              int* __restrict__ cursor,
                                              int* __restrict__ csr_src){
  int e = blockIdx.x*256 + threadIdx.x;
  if(e >= ETOT) return;
  int s, d;
  if(e < E_){ s = ei[e]; d = ei[E_ + e]; } else { s = d = e - E_; }
  int pos = atomicAdd(&cursor[d], 1);
  csr_src[pos] = s;
}

// ---------------- GEMM1: h1[N,128] = x[N,128] @ W1[128,128] ----------------
__global__ __launch_bounds__(256) void k_gemm1(const float* __restrict__ x,
                                               const float* __restrict__ W,
                                               float* __restrict__ h1){
  __shared__ float Wl[128*128];               // 64 KiB
  int tid = threadIdx.x;
  const float4* W4 = (const float4*)W;
  float4* Wl4 = (float4*)Wl;
  #pragma unroll
  for(int i=0;i<16;i++) Wl4[tid + i*256] = W4[tid + i*256];
  __syncthreads();
  int col = tid & 127;
  int rg  = tid >> 7;
  int row0 = blockIdx.x*32 + rg*16;
  if(row0 >= N) return;
  int rmax = N - row0; if(rmax > 16) rmax = 16;
  float acc[16];
  #pragma unroll
  for(int r=0;r<16;r++) acc[r]=0.f;
  const float4* x4 = (const float4*)x;        // [N][32] float4
  for(int k4=0;k4<32;k4++){
    float w0 = Wl[(4*k4+0)*128+col];
    float w1 = Wl[(4*k4+1)*128+col];
    float w2 = Wl[(4*k4+2)*128+col];
    float w3 = Wl[(4*k4+3)*128+col];
    #pragma unroll
    for(int r=0;r<16;r++){
      if(r < rmax){
        float4 xv = x4[(size_t)(row0+r)*32 + k4];
        acc[r] = fmaf(xv.x,w0, fmaf(xv.y,w1, fmaf(xv.z,w2, fmaf(xv.w,w3, acc[r]))));
      }
    }
  }
  for(int r=0;r<rmax;r++) h1[(size_t)(row0+r)*HH + col] = acc[r];
}

// ---------------- per-node attention logits, layer 1 ----------------
__global__ __launch_bounds__(256) void k_alpha1(const float* __restrict__ h1,
                                                const float* __restrict__ av_s,
                                                const float* __restrict__ av_d,
                                                float* __restrict__ as1, float* __restrict__ ad1){
  int id = blockIdx.x*256 + threadIdx.x;
  if(id >= N*HEADS) return;
  int i = id >> 3, h = id & 7;
  const float4* hv = (const float4*)(h1 + (size_t)i*HH + h*HID);
  const float4* a1 = (const float4*)(av_s + h*HID);
  const float4* a2 = (const float4*)(av_d + h*HID);
  float s=0.f, d=0.f;
  #pragma unroll
  for(int j=0;j<4;j++){
    float4 v=hv[j], p=a1[j], q=a2[j];
    s += v.x*p.x + v.y*p.y + v.z*p.z + v.w*p.w;
    d += v.x*q.x + v.y*q.y + v.z*q.z + v.w*q.w;
  }
  as1[id]=s; ad1[id]=d;
}

// ---------------- fused layer-1 aggregation: online softmax + bias + ELU ----------------
__global__ __launch_bounds__(128) void k_agg1(const int* __restrict__ off,
                                              const int* __restrict__ csr,
                                              const float* __restrict__ as1,
                                              const float* __restrict__ ad1,
                                              const float* __restrict__ h1,
                                              const float* __restrict__ b1,
                                              float* __restrict__ helu){
  int node = blockIdx.x;
  int c = threadIdx.x;          // 0..127
  int h = c >> 4;               // head
  int beg = off[node], end = off[node+1];
  float adv = ad1[node*HEADS + h];
  float m = -INFINITY, den = 0.f, num = 0.f;
  #pragma unroll 4
  for(int e=beg; e<end; e++){
    int s = csr[e];
    float v = as1[s*HEADS + h] + adv;
    v = v > 0.f ? v : NEG*v;
    float mn  = fmaxf(m, v);
    float fac = __expf(m - mn);      // 0 on first edge (m=-inf), 1 when max unchanged
    float w   = __expf(v - mn);
    den = den*fac + w;
    num = fmaf(num, fac, w * h1[(size_t)s*HH + c]);
    m = mn;
  }
  float res = num / (den + 1e-16f) + b1[c];
  helu[(size_t)node*HH + c] = res > 0.f ? res : expm1f(res);
}

// ---------------- GEMM2: h2[N,16] = helu[N,128] @ W2[128,16] ----------------
__global__ __launch_bounds__(256) void k_gemm2(const float* __restrict__ h,
                                               const float* __restrict__ W2,
                                               float* __restrict__ h2){
  __shared__ float Wl[128*16];                // 8 KiB
  int tid = threadIdx.x;
  const float4* W4 = (const float4*)W2;
  float4* Wl4 = (float4*)Wl;
  Wl4[tid]       = W4[tid];
  Wl4[tid + 256] = W4[tid + 256];
  __syncthreads();
  int i = blockIdx.x*16 + (tid >> 4);
  int c = tid & 15;
  if(i >= N) return;
  const float4* h4 = (const float4*)(h + (size_t)i*HH);
  float acc = 0.f;
  #pragma unroll
  for(int k4=0;k4<32;k4++){
    float4 v = h4[k4];
    acc = fmaf(v.x, Wl[(4*k4+0)*16+c], acc);
    acc = fmaf(v.y, Wl[(4*k4+1)*16+c], acc);
    acc = fmaf(v.z, Wl[(4*k4+2)*16+c], acc);
    acc = fmaf(v.w, Wl[(4*k4+3)*16+c], acc);
  }
  h2[(size_t)i*CLS + c] = acc;
}

// ---------------- per-node attention logits, layer 2 ----------------
__global__ __launch_bounds__(256) void k_alpha2(const float* __restrict__ h2,
                                                const float* __restrict__ av_s,
                                                const float* __restrict__ av_d,
                                                float* __restrict__ as2, float* __restrict__ ad2){
  int i = blockIdx.x*256 + threadIdx.x;
  if(i >= N) return;
  const float4* h4 = (const float4*)(h2 + (size_t)i*CLS);
  const float4* s4 = (const float4*)av_s;
  const float4* d4 = (const float4*)av_d;
  float s=0.f, d=0.f;
  #pragma unroll
  for(int j=0;j<4;j++){
    float4 v=h4[j], a=s4[j], b=d4[j];
    s += v.x*a.x + v.y*a.y + v.z*a.z + v.w*a.w;
    d += v.x*b.x + v.y*b.y + v.z*b.z + v.w*b.w;
  }
  as2[i]=s; ad2[i]=d;
}

// ---------------- fused layer-2 aggregation (heads=1) + final bias ----------------
__global__ __launch_bounds__(256) void k_agg2(const int* __restrict__ off,
                                              const int* __restrict__ csr,
                                              const float* __restrict__ as2,
                                              const float* __restrict__ ad2,
                                              const float* __restrict__ h2,
                                              const float* __restrict__ b2,
                                              float* __restrict__ outp){
  int node = blockIdx.x*16 + (threadIdx.x >> 4);
  int c = threadIdx.x & 15;
  if(node >= N) return;
  int beg = off[node], end = off[node+1];
  float adv = ad2[node];
  float m = -INFINITY, den = 0.f, num = 0.f;
  #pragma unroll 4
  for(int e=beg; e<end; e++){
    int s = csr[e];
    float v = as2[s] + adv;
    v = v > 0.f ? v : NEG*v;
    float mn  = fmaxf(m, v);
    float fac = __expf(m - mn);
    float w   = __expf(v - mn);
    den = den*fac + w;
    num = fmaf(num, fac, w * h2[(size_t)s*CLS + c]);
    m = mn;
  }
  outp[(size_t)node*CLS + c] = num / (den + 1e-16f) + b2[c];
}

extern "C" void kernel_launch(void* const* d_in, const int* in_sizes, int n_in,
                              void* d_out, int out_size, void* d_ws, size_t ws_size,
                              hipStream_t stream){
  const float* x     = (const float*)d_in[0];
  const int*   ei    = (const int*)  d_in[1];
  const float* W1    = (const float*)d_in[2];
  const float* av_s1 = (const float*)d_in[3];
  const float* av_d1 = (const float*)d_in[4];
  const float* b1    = (const float*)d_in[5];
  const float* W2    = (const float*)d_in[6];
  const float* av_s2 = (const float*)d_in[7];
  const float* av_d2 = (const float*)d_in[8];
  const float* b2    = (const float*)d_in[9];
  float* outp = (float*)d_out;

  char* p = (char*)d_ws;
  auto alloc = [&](size_t bytes){ char* q = p; p += (bytes + 255) & ~(size_t)255; return q; };
  float* h1     = (float*)alloc((size_t)N*HH*4);
  float* helu   = (float*)alloc((size_t)N*HH*4);
  float* as1    = (float*)alloc((size_t)N*HEADS*4);
  float* ad1    = (float*)alloc((size_t)N*HEADS*4);
  float* h2     = (float*)alloc((size_t)N*CLS*4);
  float* as2    = (float*)alloc((size_t)N*4);
  float* ad2    = (float*)alloc((size_t)N*4);
  int*   deg    = (int*)  alloc((size_t)N*4);
  int*   off    = (int*)  alloc((size_t)(N+1)*4);
  int*   cursor = (int*)  alloc((size_t)N*4);
  int*   csr    = (int*)  alloc((size_t)ETOT*4);

  // CSR build (shared by both layers)
  k_zero<<<(N+255)/256, 256, 0, stream>>>(deg);
  k_hist<<<(ETOT+255)/256, 256, 0, stream>>>(ei, deg);
  k_scan<<<1, 1024, 0, stream>>>(deg, off, cursor);
  k_fill<<<(ETOT+255)/256, 256, 0, stream>>>(ei, cursor, csr);

  // layer 1
  k_gemm1<<<(N+31)/32, 256, 0, stream>>>(x, W1, h1);
  k_alpha1<<<(N*HEADS+255)/256, 256, 0, stream>>>(h1, av_s1, av_d1, as1, ad1);
  k_agg1<<<N, 128, 0, stream>>>(off, csr, as1, ad1, h1, b1, helu);

  // layer 2
  k_gemm2<<<(N+15)/16, 256, 0, stream>>>(helu, W2, h2);
  k_alpha2<<<(N+255)/256, 256, 0, stream>>>(h2, av_s2, av_d2, as2, ad2);
  k_agg2<<<(N+15)/16, 256, 0, stream>>>(off, csr, as2, ad2, h2, b2, outp);
}

// Round 3
// 357.534 us; speedup vs baseline: 2.3813x; 1.5234x over previous
//
#include <hip/hip_runtime.h>
#include <hip/hip_bf16.h>
#include <limits.h>
#include <math.h>

#define N 50000
#define E_ 800000
#define ETOT 850000          // E + N self loops
#define HH 128               // HEADS*HID
#define HEADS 8
#define HID 16
#define CLS 16
#define NEG 0.2f

// ---------------- CSR build ----------------
__global__ __launch_bounds__(256) void k_zero(int* __restrict__ deg){
  int i = blockIdx.x*256 + threadIdx.x;
  if(i < N) deg[i] = 0;
}

__global__ __launch_bounds__(256) void k_hist(const int* __restrict__ ei, int* __restrict__ deg){
  int e = blockIdx.x*256 + threadIdx.x;
  if(e >= ETOT) return;
  int d = (e < E_) ? ei[E_ + e] : e - E_;
  atomicAdd(&deg[d], 1);
}

// single-block exclusive scan over deg[N] -> off[N+1]; also seeds cursor[]
__global__ __launch_bounds__(1024) void k_scan(const int* __restrict__ deg,
                                               int* __restrict__ off,
                                               int* __restrict__ cursor){
  __shared__ int part[1024];
  const int ITEMS = (N + 1023) / 1024;   // 49
  int t = threadIdx.x;
  int base = t * ITEMS;
  int s = 0;
  for(int i=0;i<ITEMS;i++){ int idx=base+i; if(idx<N) s += deg[idx]; }
  part[t] = s;
  __syncthreads();
  for(int ofs=1; ofs<1024; ofs<<=1){
    int v = part[t];
    int add = (t >= ofs) ? part[t-ofs] : 0;
    __syncthreads();
    part[t] = v + add;
    __syncthreads();
  }
  int run = (t == 0) ? 0 : part[t-1];
  for(int i=0;i<ITEMS;i++){
    int idx = base+i;
    if(idx < N){ off[idx] = run; cursor[idx] = run; run += deg[idx]; }
  }
  if(t == 1023) off[N] = part[1023];
}

__global__ __launch_bounds__(256) void k_fill(const int* __restrict__ ei,
                                              int* __restrict__ cursor,
                                              int* __restrict__ csr_src){
  int e = blockIdx.x*256 + threadIdx.x;
  if(e >= ETOT) return;
  int s, d;
  if(e < E_){ s = ei[e]; d = ei[E_ + e]; } else { s = d = e - E_; }
  int pos = atomicAdd(&cursor[d], 1);
  csr_src[pos] = s;
}

// ---------------- GEMM1: h1[N,128] = x[N,128] @ W1[128,128] ----------------
// 64 rows x 128 cols per 256-thread block; BK=32; thread tile 4x8.
#define BM 64
#define BKK 32
__global__ __launch_bounds__(256) void k_gemm1(const float* __restrict__ x,
                                               const float* __restrict__ W,
                                               float* __restrict__ h1){
  __shared__ float xT[BKK*BM];      // [k][row], 8 KiB
  __shared__ float Wl[BKK*128];     // [k][col], xor-swizzled rows, 16 KiB
  int tid = threadIdx.x;
  int row0 = blockIdx.x * BM;
  int tx = tid & 15;                // cols tx*4 and 64+tx*4
  int ty = tid >> 4;                // rows ty*4 .. +3
  float acc[4][8];
  #pragma unroll
  for(int r=0;r<4;r++)
    #pragma unroll
    for(int j=0;j<8;j++) acc[r][j]=0.f;

  int lr = tid >> 2;                // 0..63: x-load row
  int lk = (tid & 3) * 8;           // 0,8,16,24: x-load k offset
  int wr = tid >> 3;                // 0..31: W-load k-row
  int wc = (tid & 7) * 16;          // W-load col
  int xrow = row0 + lr; if(xrow >= N) xrow = N-1;
  const float* xbase = x + (size_t)xrow*128;

  for(int k0=0; k0<128; k0+=BKK){
    float4 v0 = *(const float4*)(xbase + k0 + lk);
    float4 v1 = *(const float4*)(xbase + k0 + lk + 4);
    float4 wv0, wv1, wv2, wv3;
    {
      const float4* wsrc = (const float4*)(W + (size_t)(k0+wr)*128 + wc);
      wv0 = wsrc[0]; wv1 = wsrc[1]; wv2 = wsrc[2]; wv3 = wsrc[3];
    }
    __syncthreads();   // previous iteration's LDS reads done
    xT[(lk+0)*BM + lr] = v0.x;
    xT[(lk+1)*BM + lr] = v0.y;
    xT[(lk+2)*BM + lr] = v0.z;
    xT[(lk+3)*BM + lr] = v0.w;
    xT[(lk+4)*BM + lr] = v1.x;
    xT[(lk+5)*BM + lr] = v1.y;
    xT[(lk+6)*BM + lr] = v1.z;
    xT[(lk+7)*BM + lr] = v1.w;
    {
      char* wl = (char*)Wl;
      int swz = (wr & 7) << 4;
      int b = (wr*128 + wc)*4;
      *(float4*)(wl + ((b      ) ^ swz)) = wv0;
      *(float4*)(wl + ((b + 16 ) ^ swz)) = wv1;
      *(float4*)(wl + ((b + 32 ) ^ swz)) = wv2;
      *(float4*)(wl + ((b + 48 ) ^ swz)) = wv3;
    }
    __syncthreads();
    #pragma unroll 8
    for(int k=0;k<BKK;k++){
      float4 xv = *(const float4*)&xT[k*BM + ty*4];
      const char* wl = (const char*)Wl;
      int swz = (k & 7) << 4;
      float4 wa = *(const float4*)(wl + ((k*512 + tx*16      ) ^ swz));
      float4 wb = *(const float4*)(wl + ((k*512 + 256 + tx*16) ^ swz));
      float xr[4] = {xv.x, xv.y, xv.z, xv.w};
      #pragma unroll
      for(int r=0;r<4;r++){
        acc[r][0] = fmaf(xr[r], wa.x, acc[r][0]);
        acc[r][1] = fmaf(xr[r], wa.y, acc[r][1]);
        acc[r][2] = fmaf(xr[r], wa.z, acc[r][2]);
        acc[r][3] = fmaf(xr[r], wa.w, acc[r][3]);
        acc[r][4] = fmaf(xr[r], wb.x, acc[r][4]);
        acc[r][5] = fmaf(xr[r], wb.y, acc[r][5]);
        acc[r][6] = fmaf(xr[r], wb.z, acc[r][6]);
        acc[r][7] = fmaf(xr[r], wb.w, acc[r][7]);
      }
    }
  }
  #pragma unroll
  for(int r=0;r<4;r++){
    int row = row0 + ty*4 + r;
    if(row < N){
      float* dst = h1 + (size_t)row*128;
      *(float4*)(dst + tx*4)      = make_float4(acc[r][0],acc[r][1],acc[r][2],acc[r][3]);
      *(float4*)(dst + 64 + tx*4) = make_float4(acc[r][4],acc[r][5],acc[r][6],acc[r][7]);
    }
  }
}

// ---------------- per-node attention logits, layer 1 ----------------
__global__ __launch_bounds__(256) void k_alpha1(const float* __restrict__ h1,
                                                const float* __restrict__ av_s,
                                                const float* __restrict__ av_d,
                                                float* __restrict__ as1, float* __restrict__ ad1){
  int id = blockIdx.x*256 + threadIdx.x;
  if(id >= N*HEADS) return;
  int i = id >> 3, h = id & 7;
  const float4* hv = (const float4*)(h1 + (size_t)i*HH + h*HID);
  const float4* a1 = (const float4*)(av_s + h*HID);
  const float4* a2 = (const float4*)(av_d + h*HID);
  float s=0.f, d=0.f;
  #pragma unroll
  for(int j=0;j<4;j++){
    float4 v=hv[j], p=a1[j], q=a2[j];
    s += v.x*p.x + v.y*p.y + v.z*p.z + v.w*p.w;
    d += v.x*q.x + v.y*q.y + v.z*q.z + v.w*q.w;
  }
  as1[id]=s; ad1[id]=d;
}

// ---------------- fused layer-1 aggregation: online softmax + bias + ELU ----------------
#define EDGE1(vv, xx) { float v_ = (vv) > 0.f ? (vv) : NEG*(vv);                  \
    float mn_ = fmaxf(m, v_); float fac_ = __expf(m - mn_);                        \
    float w_ = __expf(v_ - mn_);                                                   \
    den = den*fac_ + w_; num = fmaf(num, fac_, w_*(xx)); m = mn_; }

__global__ __launch_bounds__(128) void k_agg1(const int* __restrict__ off,
                                              const int* __restrict__ csr,
                                              const float* __restrict__ as1,
                                              const float* __restrict__ ad1,
                                              const float* __restrict__ h1,
                                              const float* __restrict__ b1,
                                              float* __restrict__ helu){
  int node = blockIdx.x;
  int c = threadIdx.x;          // 0..127
  int h = c >> 4;               // head
  int beg = off[node], end = off[node+1];
  float adv = ad1[node*HEADS + h];
  float m = -INFINITY, den = 0.f, num = 0.f;
  int e = beg;
  for(; e + 4 <= end; e += 4){
    int s0=csr[e], s1=csr[e+1], s2=csr[e+2], s3=csr[e+3];
    float a0=as1[s0*HEADS+h]+adv, a1=as1[s1*HEADS+h]+adv,
          a2=as1[s2*HEADS+h]+adv, a3=as1[s3*HEADS+h]+adv;
    float x0=h1[(size_t)s0*HH+c], x1=h1[(size_t)s1*HH+c],
          x2=h1[(size_t)s2*HH+c], x3=h1[(size_t)s3*HH+c];
    EDGE1(a0,x0) EDGE1(a1,x1) EDGE1(a2,x2) EDGE1(a3,x3)
  }
  for(; e < end; e++){
    int s = csr[e];
    float a = as1[s*HEADS+h]+adv;
    float xx = h1[(size_t)s*HH+c];
    EDGE1(a,xx)
  }
  float res = num / (den + 1e-16f) + b1[c];
  helu[(size_t)node*HH + c] = res > 0.f ? res : expm1f(res);
}

// ---------------- GEMM2: h2[N,16] = helu[N,128] @ W2[128,16] ----------------
__global__ __launch_bounds__(256) void k_gemm2(const float* __restrict__ h,
                                               const float* __restrict__ W2,
                                               float* __restrict__ h2){
  __shared__ float Wl[128*16];                // 8 KiB
  int tid = threadIdx.x;
  const float4* W4 = (const float4*)W2;
  float4* Wl4 = (float4*)Wl;
  Wl4[tid]       = W4[tid];
  Wl4[tid + 256] = W4[tid + 256];
  __syncthreads();
  int i = blockIdx.x*16 + (tid >> 4);
  int c = tid & 15;
  if(i >= N) return;
  const float4* h4 = (const float4*)(h + (size_t)i*HH);
  float acc = 0.f;
  #pragma unroll
  for(int k4=0;k4<32;k4++){
    float4 v = h4[k4];
    acc = fmaf(v.x, Wl[(4*k4+0)*16+c], acc);
    acc = fmaf(v.y, Wl[(4*k4+1)*16+c], acc);
    acc = fmaf(v.z, Wl[(4*k4+2)*16+c], acc);
    acc = fmaf(v.w, Wl[(4*k4+3)*16+c], acc);
  }
  h2[(size_t)i*CLS + c] = acc;
}

// ---------------- per-node attention logits, layer 2 ----------------
__global__ __launch_bounds__(256) void k_alpha2(const float* __restrict__ h2,
                                                const float* __restrict__ av_s,
                                                const float* __restrict__ av_d,
                                                float* __restrict__ as2, float* __restrict__ ad2){
  int i = blockIdx.x*256 + threadIdx.x;
  if(i >= N) return;
  const float4* h4 = (const float4*)(h2 + (size_t)i*CLS);
  const float4* s4 = (const float4*)av_s;
  const float4* d4 = (const float4*)av_d;
  float s=0.f, d=0.f;
  #pragma unroll
  for(int j=0;j<4;j++){
    float4 v=h4[j], a=s4[j], b=d4[j];
    s += v.x*a.x + v.y*a.y + v.z*a.z + v.w*a.w;
    d += v.x*b.x + v.y*b.y + v.z*b.z + v.w*b.w;
  }
  as2[i]=s; ad2[i]=d;
}

// ---------------- fused layer-2 aggregation (heads=1) + final bias ----------------
__global__ __launch_bounds__(256) void k_agg2(const int* __restrict__ off,
                                              const int* __restrict__ csr,
                                              const float* __restrict__ as2,
                                              const float* __restrict__ ad2,
                                              const float* __restrict__ h2,
                                              const float* __restrict__ b2,
                                              float* __restrict__ outp){
  int node = blockIdx.x*16 + (threadIdx.x >> 4);
  int c = threadIdx.x & 15;
  if(node >= N) return;
  int beg = off[node], end = off[node+1];
  float adv = ad2[node];
  float m = -INFINITY, den = 0.f, num = 0.f;
  int e = beg;
  for(; e + 4 <= end; e += 4){
    int s0=csr[e], s1=csr[e+1], s2=csr[e+2], s3=csr[e+3];
    float a0=as2[s0]+adv, a1=as2[s1]+adv, a2=as2[s2]+adv, a3=as2[s3]+adv;
    float x0=h2[(size_t)s0*CLS+c], x1=h2[(size_t)s1*CLS+c],
          x2=h2[(size_t)s2*CLS+c], x3=h2[(size_t)s3*CLS+c];
    EDGE1(a0,x0) EDGE1(a1,x1) EDGE1(a2,x2) EDGE1(a3,x3)
  }
  for(; e < end; e++){
    int s = csr[e];
    float a = as2[s]+adv;
    float xx = h2[(size_t)s*CLS+c];
    EDGE1(a,xx)
  }
  outp[(size_t)node*CLS + c] = num / (den + 1e-16f) + b2[c];
}

extern "C" void kernel_launch(void* const* d_in, const int* in_sizes, int n_in,
                              void* d_out, int out_size, void* d_ws, size_t ws_size,
                              hipStream_t stream){
  const float* x     = (const float*)d_in[0];
  const int*   ei    = (const int*)  d_in[1];
  const float* W1    = (const float*)d_in[2];
  const float* av_s1 = (const float*)d_in[3];
  const float* av_d1 = (const float*)d_in[4];
  const float* b1    = (const float*)d_in[5];
  const float* W2    = (const float*)d_in[6];
  const float* av_s2 = (const float*)d_in[7];
  const float* av_d2 = (const float*)d_in[8];
  const float* b2    = (const float*)d_in[9];
  float* outp = (float*)d_out;

  char* p = (char*)d_ws;
  auto alloc = [&](size_t bytes){ char* q = p; p += (bytes + 255) & ~(size_t)255; return q; };
  float* h1     = (float*)alloc((size_t)N*HH*4);
  float* helu   = (float*)alloc((size_t)N*HH*4);
  float* as1    = (float*)alloc((size_t)N*HEADS*4);
  float* ad1    = (float*)alloc((size_t)N*HEADS*4);
  float* h2     = (float*)alloc((size_t)N*CLS*4);
  float* as2    = (float*)alloc((size_t)N*4);
  float* ad2    = (float*)alloc((size_t)N*4);
  int*   deg    = (int*)  alloc((size_t)N*4);
  int*   off    = (int*)  alloc((size_t)(N+1)*4);
  int*   cursor = (int*)  alloc((size_t)N*4);
  int*   csr    = (int*)  alloc((size_t)ETOT*4);

  // CSR build (shared by both layers)
  k_zero<<<(N+255)/256, 256, 0, stream>>>(deg);
  k_hist<<<(ETOT+255)/256, 256, 0, stream>>>(ei, deg);
  k_scan<<<1, 1024, 0, stream>>>(deg, off, cursor);
  k_fill<<<(ETOT+255)/256, 256, 0, stream>>>(ei, cursor, csr);

  // layer 1
  k_gemm1<<<(N+BM-1)/BM, 256, 0, stream>>>(x, W1, h1);
  k_alpha1<<<(N*HEADS+255)/256, 256, 0, stream>>>(h1, av_s1, av_d1, as1, ad1);
  k_agg1<<<N, 128, 0, stream>>>(off, csr, as1, ad1, h1, b1, helu);

  // layer 2
  k_gemm2<<<(N+15)/16, 256, 0, stream>>>(helu, W2, h2);
  k_alpha2<<<(N+255)/256, 256, 0, stream>>>(h2, av_s2, av_d2, as2, ad2);
  k_agg2<<<(N+15)/16, 256, 0, stream>>>(off, csr, as2, ad2, h2, b2, outp);
}

// Round 4
// 242.548 us; speedup vs baseline: 3.5102x; 1.4741x over previous
//
#include <hip/hip_runtime.h>
#include <hip/hip_bf16.h>
#include <limits.h>
#include <math.h>

#define N 50000
#define E_ 800000
#define ETOT 850000          // E + N self loops
#define HH 128               // HEADS*HID
#define HEADS 8
#define HID 16
#define CLS 16
#define NEG 0.2f
#define NB ((N + 255) / 256) // 196 scan blocks

// ---------------- CSR build ----------------
__global__ __launch_bounds__(256) void k_zero(int* __restrict__ deg){
  int i = blockIdx.x*256 + threadIdx.x;
  if(i < N) deg[i] = 0;
}

__global__ __launch_bounds__(256) void k_hist(const int* __restrict__ ei, int* __restrict__ deg){
  int e = blockIdx.x*256 + threadIdx.x;
  if(e >= ETOT) return;
  int d = (e < E_) ? ei[E_ + e] : e - E_;
  atomicAdd(&deg[d], 1);
}

// stage 1: per-block chunk sums
__global__ __launch_bounds__(256) void k_scan1(const int* __restrict__ deg, int* __restrict__ bsum){
  __shared__ int sm[256];
  int t = threadIdx.x;
  int i = blockIdx.x*256 + t;
  sm[t] = (i < N) ? deg[i] : 0;
  __syncthreads();
  #pragma unroll
  for(int ofs=128; ofs>0; ofs>>=1){
    if(t < ofs) sm[t] += sm[t+ofs];
    __syncthreads();
  }
  if(t == 0) bsum[blockIdx.x] = sm[0];
}

// stage 2: one block scans the 196 block sums -> exclusive boff; off[N]=total
__global__ __launch_bounds__(256) void k_scan2(const int* __restrict__ bsum,
                                               int* __restrict__ boff,
                                               int* __restrict__ off){
  __shared__ int sm[256];
  int t = threadIdx.x;
  sm[t] = (t < NB) ? bsum[t] : 0;
  __syncthreads();
  #pragma unroll
  for(int ofs=1; ofs<256; ofs<<=1){
    int v = sm[t];
    int add = (t >= ofs) ? sm[t-ofs] : 0;
    __syncthreads();
    sm[t] = v + add;
    __syncthreads();
  }
  if(t < NB) boff[t] = (t == 0) ? 0 : sm[t-1];
  if(t == 255) off[N] = sm[NB-1];
}

// stage 3: local exclusive scan + block offset -> off[], cursor[]
__global__ __launch_bounds__(256) void k_scan3(const int* __restrict__ deg,
                                               const int* __restrict__ boff,
                                               int* __restrict__ off,
                                               int* __restrict__ cursor){
  __shared__ int sm[256];
  int t = threadIdx.x;
  int i = blockIdx.x*256 + t;
  int v0 = (i < N) ? deg[i] : 0;
  sm[t] = v0;
  __syncthreads();
  #pragma unroll
  for(int ofs=1; ofs<256; ofs<<=1){
    int v = sm[t];
    int add = (t >= ofs) ? sm[t-ofs] : 0;
    __syncthreads();
    sm[t] = v + add;
    __syncthreads();
  }
  if(i < N){
    int excl = boff[blockIdx.x] + sm[t] - v0;   // inclusive - self = exclusive
    off[i] = excl;
    cursor[i] = excl;
  }
}

__global__ __launch_bounds__(256) void k_fill(const int* __restrict__ ei,
                                              int* __restrict__ cursor,
                                              int* __restrict__ csr_src){
  int e = blockIdx.x*256 + threadIdx.x;
  if(e >= ETOT) return;
  int s, d;
  if(e < E_){ s = ei[e]; d = ei[E_ + e]; } else { s = d = e - E_; }
  int pos = atomicAdd(&cursor[d], 1);
  csr_src[pos] = s;
}

// ---------------- GEMM1: h1[N,128] = x[N,128] @ W1[128,128] ----------------
// 64 rows x 128 cols per 256-thread block; BK=32; thread tile 4x8.
#define BM 64
#define BKK 32
__global__ __launch_bounds__(256) void k_gemm1(const float* __restrict__ x,
                                               const float* __restrict__ W,
                                               float* __restrict__ h1){
  __shared__ float xT[BKK*BM];      // [k][row], 8 KiB
  __shared__ float Wl[BKK*128];     // [k][col], xor-swizzled rows, 16 KiB
  int tid = threadIdx.x;
  int row0 = blockIdx.x * BM;
  int tx = tid & 15;                // cols tx*4 and 64+tx*4
  int ty = tid >> 4;                // rows ty*4 .. +3
  float acc[4][8];
  #pragma unroll
  for(int r=0;r<4;r++)
    #pragma unroll
    for(int j=0;j<8;j++) acc[r][j]=0.f;

  int lr = tid >> 2;                // 0..63: x-load row
  int lk = (tid & 3) * 8;           // 0,8,16,24: x-load k offset
  int wr = tid >> 3;                // 0..31: W-load k-row
  int wc = (tid & 7) * 16;          // W-load col
  int xrow = row0 + lr; if(xrow >= N) xrow = N-1;
  const float* xbase = x + (size_t)xrow*128;

  for(int k0=0; k0<128; k0+=BKK){
    float4 v0 = *(const float4*)(xbase + k0 + lk);
    float4 v1 = *(const float4*)(xbase + k0 + lk + 4);
    float4 wv0, wv1, wv2, wv3;
    {
      const float4* wsrc = (const float4*)(W + (size_t)(k0+wr)*128 + wc);
      wv0 = wsrc[0]; wv1 = wsrc[1]; wv2 = wsrc[2]; wv3 = wsrc[3];
    }
    __syncthreads();   // previous iteration's LDS reads done
    xT[(lk+0)*BM + lr] = v0.x;
    xT[(lk+1)*BM + lr] = v0.y;
    xT[(lk+2)*BM + lr] = v0.z;
    xT[(lk+3)*BM + lr] = v0.w;
    xT[(lk+4)*BM + lr] = v1.x;
    xT[(lk+5)*BM + lr] = v1.y;
    xT[(lk+6)*BM + lr] = v1.z;
    xT[(lk+7)*BM + lr] = v1.w;
    {
      char* wl = (char*)Wl;
      int swz = (wr & 7) << 4;
      int b = (wr*128 + wc)*4;
      *(float4*)(wl + ((b      ) ^ swz)) = wv0;
      *(float4*)(wl + ((b + 16 ) ^ swz)) = wv1;
      *(float4*)(wl + ((b + 32 ) ^ swz)) = wv2;
      *(float4*)(wl + ((b + 48 ) ^ swz)) = wv3;
    }
    __syncthreads();
    #pragma unroll 8
    for(int k=0;k<BKK;k++){
      float4 xv = *(const float4*)&xT[k*BM + ty*4];
      const char* wl = (const char*)Wl;
      int swz = (k & 7) << 4;
      float4 wa = *(const float4*)(wl + ((k*512 + tx*16      ) ^ swz));
      float4 wb = *(const float4*)(wl + ((k*512 + 256 + tx*16) ^ swz));
      float xr[4] = {xv.x, xv.y, xv.z, xv.w};
      #pragma unroll
      for(int r=0;r<4;r++){
        acc[r][0] = fmaf(xr[r], wa.x, acc[r][0]);
        acc[r][1] = fmaf(xr[r], wa.y, acc[r][1]);
        acc[r][2] = fmaf(xr[r], wa.z, acc[r][2]);
        acc[r][3] = fmaf(xr[r], wa.w, acc[r][3]);
        acc[r][4] = fmaf(xr[r], wb.x, acc[r][4]);
        acc[r][5] = fmaf(xr[r], wb.y, acc[r][5]);
        acc[r][6] = fmaf(xr[r], wb.z, acc[r][6]);
        acc[r][7] = fmaf(xr[r], wb.w, acc[r][7]);
      }
    }
  }
  #pragma unroll
  for(int r=0;r<4;r++){
    int row = row0 + ty*4 + r;
    if(row < N){
      float* dst = h1 + (size_t)row*128;
      *(float4*)(dst + tx*4)      = make_float4(acc[r][0],acc[r][1],acc[r][2],acc[r][3]);
      *(float4*)(dst + 64 + tx*4) = make_float4(acc[r][4],acc[r][5],acc[r][6],acc[r][7]);
    }
  }
}

// ---------------- per-node attention logits, layer 1 ----------------
__global__ __launch_bounds__(256) void k_alpha1(const float* __restrict__ h1,
                                                const float* __restrict__ av_s,
                                                const float* __restrict__ av_d,
                                                float* __restrict__ as1, float* __restrict__ ad1){
  int id = blockIdx.x*256 + threadIdx.x;
  if(id >= N*HEADS) return;
  int i = id >> 3, h = id & 7;
  const float4* hv = (const float4*)(h1 + (size_t)i*HH + h*HID);
  const float4* a1 = (const float4*)(av_s + h*HID);
  const float4* a2 = (const float4*)(av_d + h*HID);
  float s=0.f, d=0.f;
  #pragma unroll
  for(int j=0;j<4;j++){
    float4 v=hv[j], p=a1[j], q=a2[j];
    s += v.x*p.x + v.y*p.y + v.z*p.z + v.w*p.w;
    d += v.x*q.x + v.y*q.y + v.z*q.z + v.w*q.w;
  }
  as1[id]=s; ad1[id]=d;
}

// ---------------- fused layer-1 aggregation: online softmax + bias + ELU ----------------
#define EDGE1(vv, xx) { float v_ = (vv) > 0.f ? (vv) : NEG*(vv);                  \
    float mn_ = fmaxf(m, v_); float fac_ = __expf(m - mn_);                        \
    float w_ = __expf(v_ - mn_);                                                   \
    den = den*fac_ + w_; num = fmaf(num, fac_, w_*(xx)); m = mn_; }

__global__ __launch_bounds__(128) void k_agg1(const int* __restrict__ off,
                                              const int* __restrict__ csr,
                                              const float* __restrict__ as1,
                                              const float* __restrict__ ad1,
                                              const float* __restrict__ h1,
                                              const float* __restrict__ b1,
                                              float* __restrict__ helu){
  int node = blockIdx.x;
  int c = threadIdx.x;          // 0..127
  int h = c >> 4;               // head
  int beg = off[node], end = off[node+1];
  float adv = ad1[node*HEADS + h];
  float m = -INFINITY, den = 0.f, num = 0.f;
  int e = beg;
  for(; e + 4 <= end; e += 4){
    int s0=csr[e], s1=csr[e+1], s2=csr[e+2], s3=csr[e+3];
    float a0=as1[s0*HEADS+h]+adv, a1=as1[s1*HEADS+h]+adv,
          a2=as1[s2*HEADS+h]+adv, a3=as1[s3*HEADS+h]+adv;
    float x0=h1[(size_t)s0*HH+c], x1=h1[(size_t)s1*HH+c],
          x2=h1[(size_t)s2*HH+c], x3=h1[(size_t)s3*HH+c];
    EDGE1(a0,x0) EDGE1(a1,x1) EDGE1(a2,x2) EDGE1(a3,x3)
  }
  for(; e < end; e++){
    int s = csr[e];
    float a = as1[s*HEADS+h]+adv;
    float xx = h1[(size_t)s*HH+c];
    EDGE1(a,xx)
  }
  float res = num / (den + 1e-16f) + b1[c];
  helu[(size_t)node*HH + c] = res > 0.f ? res : expm1f(res);
}

// ---------------- GEMM2: h2[N,16] = helu[N,128] @ W2[128,16] ----------------
__global__ __launch_bounds__(256) void k_gemm2(const float* __restrict__ h,
                                               const float* __restrict__ W2,
                                               float* __restrict__ h2){
  __shared__ float Wl[128*16];                // 8 KiB
  int tid = threadIdx.x;
  const float4* W4 = (const float4*)W2;
  float4* Wl4 = (float4*)Wl;
  Wl4[tid]       = W4[tid];
  Wl4[tid + 256] = W4[tid + 256];
  __syncthreads();
  int i = blockIdx.x*16 + (tid >> 4);
  int c = tid & 15;
  if(i >= N) return;
  const float4* h4 = (const float4*)(h + (size_t)i*HH);
  float acc = 0.f;
  #pragma unroll
  for(int k4=0;k4<32;k4++){
    float4 v = h4[k4];
    acc = fmaf(v.x, Wl[(4*k4+0)*16+c], acc);
    acc = fmaf(v.y, Wl[(4*k4+1)*16+c], acc);
    acc = fmaf(v.z, Wl[(4*k4+2)*16+c], acc);
    acc = fmaf(v.w, Wl[(4*k4+3)*16+c], acc);
  }
  h2[(size_t)i*CLS + c] = acc;
}

// ---------------- per-node attention logits, layer 2 ----------------
__global__ __launch_bounds__(256) void k_alpha2(const float* __restrict__ h2,
                                                const float* __restrict__ av_s,
                                                const float* __restrict__ av_d,
                                                float* __restrict__ as2, float* __restrict__ ad2){
  int i = blockIdx.x*256 + threadIdx.x;
  if(i >= N) return;
  const float4* h4 = (const float4*)(h2 + (size_t)i*CLS);
  const float4* s4 = (const float4*)av_s;
  const float4* d4 = (const float4*)av_d;
  float s=0.f, d=0.f;
  #pragma unroll
  for(int j=0;j<4;j++){
    float4 v=h4[j], a=s4[j], b=d4[j];
    s += v.x*a.x + v.y*a.y + v.z*a.z + v.w*a.w;
    d += v.x*b.x + v.y*b.y + v.z*b.z + v.w*b.w;
  }
  as2[i]=s; ad2[i]=d;
}

// ---------------- fused layer-2 aggregation (heads=1) + final bias ----------------
__global__ __launch_bounds__(256) void k_agg2(const int* __restrict__ off,
                                              const int* __restrict__ csr,
                                              const float* __restrict__ as2,
                                              const float* __restrict__ ad2,
                                              const float* __restrict__ h2,
                                              const float* __restrict__ b2,
                                              float* __restrict__ outp){
  int node = blockIdx.x*16 + (threadIdx.x >> 4);
  int c = threadIdx.x & 15;
  if(node >= N) return;
  int beg = off[node], end = off[node+1];
  float adv = ad2[node];
  float m = -INFINITY, den = 0.f, num = 0.f;
  int e = beg;
  for(; e + 4 <= end; e += 4){
    int s0=csr[e], s1=csr[e+1], s2=csr[e+2], s3=csr[e+3];
    float a0=as2[s0]+adv, a1=as2[s1]+adv, a2=as2[s2]+adv, a3=as2[s3]+adv;
    float x0=h2[(size_t)s0*CLS+c], x1=h2[(size_t)s1*CLS+c],
          x2=h2[(size_t)s2*CLS+c], x3=h2[(size_t)s3*CLS+c];
    EDGE1(a0,x0) EDGE1(a1,x1) EDGE1(a2,x2) EDGE1(a3,x3)
  }
  for(; e < end; e++){
    int s = csr[e];
    float a = as2[s]+adv;
    float xx = h2[(size_t)s*CLS+c];
    EDGE1(a,xx)
  }
  outp[(size_t)node*CLS + c] = num / (den + 1e-16f) + b2[c];
}

extern "C" void kernel_launch(void* const* d_in, const int* in_sizes, int n_in,
                              void* d_out, int out_size, void* d_ws, size_t ws_size,
                              hipStream_t stream){
  const float* x     = (const float*)d_in[0];
  const int*   ei    = (const int*)  d_in[1];
  const float* W1    = (const float*)d_in[2];
  const float* av_s1 = (const float*)d_in[3];
  const float* av_d1 = (const float*)d_in[4];
  const float* b1    = (const float*)d_in[5];
  const float* W2    = (const float*)d_in[6];
  const float* av_s2 = (const float*)d_in[7];
  const float* av_d2 = (const float*)d_in[8];
  const float* b2    = (const float*)d_in[9];
  float* outp = (float*)d_out;

  char* p = (char*)d_ws;
  auto alloc = [&](size_t bytes){ char* q = p; p += (bytes + 255) & ~(size_t)255; return q; };
  float* h1     = (float*)alloc((size_t)N*HH*4);
  float* helu   = (float*)alloc((size_t)N*HH*4);
  float* as1    = (float*)alloc((size_t)N*HEADS*4);
  float* ad1    = (float*)alloc((size_t)N*HEADS*4);
  float* h2     = (float*)alloc((size_t)N*CLS*4);
  float* as2    = (float*)alloc((size_t)N*4);
  float* ad2    = (float*)alloc((size_t)N*4);
  int*   deg    = (int*)  alloc((size_t)N*4);
  int*   off    = (int*)  alloc((size_t)(N+1)*4);
  int*   cursor = (int*)  alloc((size_t)N*4);
  int*   csr    = (int*)  alloc((size_t)ETOT*4);
  int*   bsum   = (int*)  alloc((size_t)NB*4);
  int*   boff   = (int*)  alloc((size_t)NB*4);

  // CSR build (shared by both layers)
  k_zero<<<(N+255)/256, 256, 0, stream>>>(deg);
  k_hist<<<(ETOT+255)/256, 256, 0, stream>>>(ei, deg);
  k_scan1<<<NB, 256, 0, stream>>>(deg, bsum);
  k_scan2<<<1, 256, 0, stream>>>(bsum, boff, off);
  k_scan3<<<NB, 256, 0, stream>>>(deg, boff, off, cursor);
  k_fill<<<(ETOT+255)/256, 256, 0, stream>>>(ei, cursor, csr);

  // layer 1
  k_gemm1<<<(N+BM-1)/BM, 256, 0, stream>>>(x, W1, h1);
  k_alpha1<<<(N*HEADS+255)/256, 256, 0, stream>>>(h1, av_s1, av_d1, as1, ad1);
  k_agg1<<<N, 128, 0, stream>>>(off, csr, as1, ad1, h1, b1, helu);

  // layer 2
  k_gemm2<<<(N+15)/16, 256, 0, stream>>>(helu, W2, h2);
  k_alpha2<<<(N+255)/256, 256, 0, stream>>>(h2, av_s2, av_d2, as2, ad2);
  k_agg2<<<(N+15)/16, 256, 0, stream>>>(off, csr, as2, ad2, h2, b2, outp);
}